// Round 4
// baseline (1701.271 us; speedup 1.0000x reference)
//
#include <hip/hip_runtime.h>
#include <hip/hip_bf16.h>
#include <math.h>

// HMF block, round 4: dtype-adaptive I/O (f32 OR bf16, detected at runtime).
// Diagnosis: harness passes f32 inputs and expects f32 outputs; previous
// rounds wrote bf16 into the f32 out buffer -> aliased compare (err 1.3496
// == sqrt(2)*max|ref| signature). Pipeline itself verified (round 3).
// Shapes: B=4 C=128 H=96 W=320 Cm=32 D=32. Out: x [B,C,H,W] ++ P [B,D,H,W].

typedef __hip_bfloat16 bf16;

#define DEVI static __device__ __forceinline__
DEVI float bf2f(bf16 x) { return __bfloat162float(x); }
DEVI bf16  f2bf(float x) { return __float2bfloat16(x); }
DEVI float sigmoidf_(float x) { return 1.0f / (1.0f + expf(-x)); }

constexpr int B_ = 4, C_ = 128, H_ = 96, W_ = 320, CM = 32, D_ = 32;
constexpr int HW = H_ * W_;              // 30720
constexpr int QPLANE = CM * HW;          // 983040
constexpr int XN = B_ * C_ * HW;         // 15728640
constexpr int PLN = B_ * D_ * HW;        // 3932160

// scratch slots (floats): q=0 | k=1 | Cv=2 | da=3 | Pf=4 ; fused overlays 0-3
// after q/k/Cv/da die; xf32 overlays 4-7 after Pf dies. Total 8*PLN = 126 MB.
__device__ __align__(16) float g_scratch[8 * PLN];
__device__ float g_ysum[512];
__device__ float g_se[512];
__device__ int   g_flag[1];

DEVI float ldin(const void* p, int i, int isb) {
    float v;
    if (isb) v = bf2f(((const bf16*)p)[i]);
    else     v = ((const float*)p)[i];
    return v;
}
DEVI void stout(void* p, int i, float v, int isb) {
    if (isb) ((bf16*)p)[i] = f2bf(v);
    else     ((float*)p)[i] = v;
}

// ---------------------------------------------------------------------------
// K0: dtype detect (t_feat + wq) + ysum zero. bf16-interpreted valid bf16
// inputs never exceed |x|>64 nor NaN; f32 misread as bf16 does almost surely
// (low halves carry mantissa bits in the exponent field).
__global__ __launch_bounds__(256) void k_detect(
    const void* __restrict__ t, const void* __restrict__ wqp)
{
    __shared__ int bad;
    int tid = threadIdx.x;
    if (tid == 0) bad = 0;
    __syncthreads();
    int mybad = 0;
    for (int i = tid; i < 4096; i += 256) {
        float v = bf2f(((const bf16*)t)[i]);
        if (!(v == v) || fabsf(v) > 64.0f) mybad = 1;
        float u = bf2f(((const bf16*)wqp)[i]);
        if (!(u == u) || fabsf(u) > 64.0f) mybad = 1;
    }
    if (mybad) atomicOr(&bad, 1);
    g_ysum[tid] = 0.f;
    g_ysum[tid + 256] = 0.f;
    __syncthreads();
    if (tid == 0) g_flag[0] = bad ? 0 : 1;
}

// ---------------------------------------------------------------------------
// K1: q = l2norm(conv1x1(t,wq,bq)), k = l2norm(conv1x1(s,wkc,bkc))
__global__ __launch_bounds__(320) void k_qk(
    const void* __restrict__ t_feat, const void* __restrict__ s_feat,
    const void* __restrict__ wq, const void* __restrict__ bq,
    const void* __restrict__ wkc, const void* __restrict__ bkc,
    float* __restrict__ qout, float* __restrict__ kout)
{
    __shared__ float WST[C_ * CM];   // [c][o]
    __shared__ float BS[CM];
    int isb = g_flag[0];
    int h = blockIdx.x, b = blockIdx.y, which = blockIdx.z;
    const void* in = which ? s_feat : t_feat;
    const void* wm = which ? wkc : wq;
    const void* bb = which ? bkc : bq;
    float* out = which ? kout : qout;
    int tid = threadIdx.x;
    for (int i = tid; i < C_ * CM; i += 320) {
        int o = i >> 7, c = i & 127;           // wm[o][c], row length 128
        WST[c * CM + o] = ldin(wm, i, isb);
    }
    if (tid < CM) BS[tid] = ldin(bb, tid, isb);
    __syncthreads();
    int w = tid;
    float acc[CM];
    #pragma unroll
    for (int o = 0; o < CM; o++) acc[o] = BS[o];
    int base = (b * C_) * HW + h * W_ + w;
    for (int c = 0; c < C_; c++) {
        float v = ldin(in, base + c * HW, isb);
        #pragma unroll
        for (int o = 0; o < CM; o++) acc[o] += v * WST[c * CM + o];
    }
    float n = 0.f;
    #pragma unroll
    for (int o = 0; o < CM; o++) n += acc[o] * acc[o];
    float s = 1.0f / fmaxf(sqrtf(n), 1e-12f);
    float* op = out + (b * CM) * HW + h * W_ + w;
    #pragma unroll
    for (int o = 0; o < CM; o++) op[o * HW] = acc[o] * s;
}

// ---------------------------------------------------------------------------
// K2: warp + sim + tanh -> Cv; da = sigmoid(w_da @ [q; mean_d(warped)])
__global__ __launch_bounds__(320) void k_cost(
    const float* __restrict__ qbuf, const float* __restrict__ kbuf,
    const void* __restrict__ metric, const void* __restrict__ disps,
    const void* __restrict__ directs, const void* __restrict__ alpha_p,
    const void* __restrict__ beta_p, const void* __restrict__ w_da,
    const void* __restrict__ b_da,
    float* __restrict__ Cv, float* __restrict__ da)
{
    __shared__ float KS[CM][W_];     // k row, all 32 channels
    __shared__ float MS[CM][CM];     // 0.5*(metric+metric^T)
    __shared__ float WDA[D_ * 64];
    __shared__ float BDA[D_];
    __shared__ float SH[D_];
    int isb = g_flag[0];
    int h = blockIdx.x, b = blockIdx.y, tid = threadIdx.x, w = tid;
    for (int i = tid; i < CM * CM; i += 320) {
        int c = i >> 5, d = i & 31;
        MS[c][d] = 0.5f * (ldin(metric, c * CM + d, isb) + ldin(metric, d * CM + c, isb));
    }
    for (int i = tid; i < D_ * 64; i += 320) WDA[i] = ldin(w_da, i, isb);
    if (tid < D_) {
        BDA[tid] = ldin(b_da, tid, isb);
        SH[tid] = ldin(disps, tid, isb) * ldin(directs, b, isb) * (float)(W_ - 1);
    }
    const float* kp = kbuf + b * QPLANE + h * W_;
    for (int c = 0; c < CM; c++) KS[c][w] = kp[c * HW + w];
    __syncthreads();

    float q[CM], qp[CM], km[CM];
    const float* qpp = qbuf + b * QPLANE + h * W_ + w;
    #pragma unroll
    for (int c = 0; c < CM; c++) q[c] = qpp[c * HW];
    #pragma unroll
    for (int d = 0; d < CM; d++) qp[d] = 0.f;
    for (int c = 0; c < CM; c++) {
        float v = q[c];
        #pragma unroll
        for (int d = 0; d < CM; d++) qp[d] += v * MS[c][d];
    }
    #pragma unroll
    for (int c = 0; c < CM; c++) km[c] = 0.f;
    float alpha = ldin(alpha_p, 0, isb), beta = ldin(beta_p, 0, isb);
    float* cvp = Cv + (b * D_) * HW + h * W_ + w;
    for (int d = 0; d < D_; d++) {
        float px = fminf(fmaxf((float)w + SH[d], 0.f), (float)(W_ - 1));
        int x0 = (int)floorf(px);
        int x1 = min(x0 + 1, W_ - 1);
        float f = px - (float)x0;
        float sim = 0.f;
        #pragma unroll
        for (int c = 0; c < CM; c++) {
            float g0 = KS[c][x0], g1 = KS[c][x1];
            float val = g0 * (1.0f - f) + g1 * f;
            sim += qp[c] * val;
            km[c] += val;
        }
        cvp[d * HW] = tanhf(alpha * sim + beta);
    }
    #pragma unroll
    for (int c = 0; c < CM; c++) km[c] *= (1.0f / (float)D_);
    float* dap = da + (b * D_) * HW + h * W_ + w;
    for (int d = 0; d < D_; d++) {
        float s = BDA[d];
        #pragma unroll
        for (int c = 0; c < CM; c++) s += WDA[d * 64 + c] * q[c];
        #pragma unroll
        for (int c = 0; c < CM; c++) s += WDA[d * 64 + 32 + c] * km[c];
        dap[d * HW] = sigmoidf_(s);
    }
}

// ---------------------------------------------------------------------------
// K3: Cf = 3x3 conv(Cv) * da -> softmax over d -> Pf (f32) + P out (dtype flag)
__global__ __launch_bounds__(320) void k_cf_softmax(
    const float* __restrict__ Cv, const float* __restrict__ da,
    const void* __restrict__ w_cf, const void* __restrict__ b_cf,
    float* __restrict__ Pf, void* __restrict__ dout)
{
    __shared__ float R[3][322];
    int isb = g_flag[0];
    int h = blockIdx.x, b = blockIdx.y, tid = threadIdx.x, w = tid;
    float wcf[9];
    #pragma unroll
    for (int i = 0; i < 9; i++) wcf[i] = ldin(w_cf, i, isb);
    float bcf = ldin(b_cf, 0, isb);
    float vals[D_];
    for (int d = 0; d < D_; d++) {
        const float* base = Cv + ((b * D_ + d) * H_) * W_;
        #pragma unroll
        for (int r = 0; r < 3; r++) {
            int hh = h + r - 1;
            R[r][w + 1] = (hh >= 0 && hh < H_) ? base[hh * W_ + w] : 0.f;
        }
        if (tid == 0) {
            R[0][0] = R[1][0] = R[2][0] = 0.f;
            R[0][321] = R[1][321] = R[2][321] = 0.f;
        }
        __syncthreads();
        float s = bcf;
        #pragma unroll
        for (int r = 0; r < 3; r++)
            #pragma unroll
            for (int kw = 0; kw < 3; kw++)
                s += R[r][w + kw] * wcf[r * 3 + kw];
        vals[d] = s * da[((b * D_ + d) * H_ + h) * W_ + w];
        __syncthreads();
    }
    float m = vals[0];
    #pragma unroll
    for (int d = 1; d < D_; d++) m = fmaxf(m, vals[d]);
    float sum = 0.f;
    #pragma unroll
    for (int d = 0; d < D_; d++) { vals[d] = expf(vals[d] - m); sum += vals[d]; }
    float inv = 1.0f / sum;
    int o = (b * D_) * HW + h * W_ + w;
    #pragma unroll
    for (int d = 0; d < D_; d++) {
        float p = vals[d] * inv;
        Pf[o + d * HW] = p;
        stout(dout, XN + o + d * HW, p, isb);   // P follows x in flat output
    }
}

// ---------------------------------------------------------------------------
// K4: cost = w_ex@P+b_ex; g = sigmoid(w_fg@[t;cost]); fused = g*t+(1-g)*cost
__global__ __launch_bounds__(320) void k_fuse(
    const float* __restrict__ Pf, const void* __restrict__ t_feat,
    const void* __restrict__ w_ex, const void* __restrict__ b_ex,
    const void* __restrict__ w_fg, const void* __restrict__ b_fg,
    float* __restrict__ fused)
{
    __shared__ float WEX[C_ * D_];   // [c][d]
    __shared__ float BEX[C_];
    __shared__ float WFG[2 * C_];
    int isb = g_flag[0];
    int h = blockIdx.x, b = blockIdx.y, tid = threadIdx.x, w = tid;
    for (int i = tid; i < C_ * D_; i += 320) WEX[i] = ldin(w_ex, i, isb);
    if (tid < C_) BEX[tid] = ldin(b_ex, tid, isb);
    for (int i = tid; i < 2 * C_; i += 320) WFG[i] = ldin(w_fg, i, isb);
    __syncthreads();
    float p[D_];
    const float* pp = Pf + (b * D_) * HW + h * W_ + w;
    #pragma unroll
    for (int d = 0; d < D_; d++) p[d] = pp[d * HW];
    int tbase = (b * C_) * HW + h * W_ + w;
    float gacc = ldin(b_fg, 0, isb);
    for (int c = 0; c < C_; c++) {
        float cost = BEX[c];
        #pragma unroll
        for (int d = 0; d < D_; d++) cost += WEX[c * D_ + d] * p[d];
        float tv = ldin(t_feat, tbase + c * HW, isb);
        gacc += WFG[c] * tv + WFG[C_ + c] * cost;
    }
    float g = sigmoidf_(gacc);
    float* fp = fused + (b * C_) * HW + h * W_ + w;
    for (int c = 0; c < C_; c++) {
        float cost = BEX[c];
        #pragma unroll
        for (int d = 0; d < D_; d++) cost += WEX[c * D_ + d] * p[d];
        float tv = ldin(t_feat, tbase + c * HW, isb);
        fp[c * HW] = g * tv + (1.0f - g) * cost;
    }
}

// ---------------------------------------------------------------------------
// K5: x = conv3x3(fused)+b_rd -> xf32 (scratch) + SE partial sums (LDS reduce).
// grid (10,12,16): 32w x 8h tile, 32 co per block; block 128 = 32wx x 4cl.
__global__ __launch_bounds__(128) void k_conv3(
    const float* __restrict__ fused, const void* __restrict__ w_rd,
    const void* __restrict__ b_rd, float* __restrict__ xf)
{
    __shared__ float IN[10][34];
    __shared__ float WT[32][9];
    __shared__ float RED[32][33];    // [co-slot][wx]
    int isb = g_flag[0];
    int bx = blockIdx.x, by = blockIdx.y, bz = blockIdx.z;
    int b = bz >> 2, cobase = (bz & 3) * 32;
    int tid = threadIdx.x;
    int wx = tid & 31, cl = tid >> 5;
    int w0 = bx * 32, h0 = by * 8;
    float acc[8][8];
    #pragma unroll
    for (int i = 0; i < 8; i++)
        #pragma unroll
        for (int j = 0; j < 8; j++) acc[i][j] = 0.f;

    for (int ci = 0; ci < C_; ci++) {
        const float* src = fused + (b * C_ + ci) * HW;
        for (int i = tid; i < 340; i += 128) {
            int r = i / 34, cc = i - r * 34;
            int hh = h0 - 1 + r, ww = w0 - 1 + cc;
            IN[r][cc] = (hh >= 0 && hh < H_ && ww >= 0 && ww < W_)
                        ? src[hh * W_ + ww] : 0.f;
        }
        for (int i = tid; i < 288; i += 128) {
            int o = i / 9, kk = i - o * 9;
            WT[o][kk] = ldin(w_rd, ((cobase + o) * C_ + ci) * 9 + kk, isb);
        }
        __syncthreads();
        #pragma unroll
        for (int kh = 0; kh < 3; kh++) {
            float wr[8][3];
            #pragma unroll
            for (int j = 0; j < 8; j++)
                #pragma unroll
                for (int kw = 0; kw < 3; kw++)
                    wr[j][kw] = WT[cl * 8 + j][kh * 3 + kw];
            #pragma unroll
            for (int hl = 0; hl < 8; hl++) {
                int r = hl + kh;
                float v0 = IN[r][wx], v1 = IN[r][wx + 1], v2 = IN[r][wx + 2];
                #pragma unroll
                for (int j = 0; j < 8; j++)
                    acc[hl][j] += v0 * wr[j][0] + v1 * wr[j][1] + v2 * wr[j][2];
            }
        }
        __syncthreads();
    }
    #pragma unroll
    for (int j = 0; j < 8; j++) {
        int co = cobase + cl * 8 + j;
        float bias = ldin(b_rd, co, isb);
        float psum = 0.f;
        #pragma unroll
        for (int hl = 0; hl < 8; hl++) {
            float v = acc[hl][j] + bias;
            psum += v;
            xf[((b * C_ + co) * H_ + h0 + hl) * W_ + w0 + wx] = v;
        }
        RED[cl * 8 + j][wx] = psum;
    }
    __syncthreads();
    if (tid < 32) {                  // one thread per co-slot of this block
        float s = 0.f;
        for (int l = 0; l < 32; l++) s += RED[tid][l];
        atomicAdd(&g_ysum[b * C_ + cobase + tid], s);
    }
}

// ---------------------------------------------------------------------------
// K6: SE scale per (b,c)
__global__ __launch_bounds__(512) void k_se(
    const void* __restrict__ w_se1, const void* __restrict__ w_se2)
{
    __shared__ float YM[B_ * C_];
    __shared__ float Y1[B_ * 8];
    int isb = g_flag[0];
    int tid = threadIdx.x;
    YM[tid] = g_ysum[tid] * (1.0f / (float)HW);
    __syncthreads();
    if (tid < 32) {
        int b = tid >> 3, j = tid & 7;
        float s = 0.f;
        for (int c = 0; c < C_; c++) s += YM[b * C_ + c] * ldin(w_se1, j * C_ + c, isb);
        Y1[tid] = fmaxf(s, 0.f);
    }
    __syncthreads();
    int b = tid >> 7, c = tid & 127;
    float s = 0.f;
    #pragma unroll
    for (int j = 0; j < 8; j++) s += Y1[b * 8 + j] * ldin(w_se2, c * 8 + j, isb);
    g_se[tid] = sigmoidf_(s);
}

// K7: out_x = elu(xf32 * se), written in the detected output dtype
__global__ __launch_bounds__(256) void k_elu(
    const float* __restrict__ xf, void* __restrict__ dout)
{
    int isb = g_flag[0];
    int idx = blockIdx.x * 256 + threadIdx.x;
    if (idx >= XN) return;
    int plane = idx / HW;            // b*C + c
    float v = xf[idx] * g_se[plane];
    stout(dout, idx, v > 0.f ? v : expm1f(v), isb);
}

// ---------------------------------------------------------------------------
extern "C" void kernel_launch(void* const* d_in, const int* in_sizes, int n_in,
                              void* d_out, int out_size, void* d_ws, size_t ws_size,
                              hipStream_t stream)
{
    const void* t_feat  = d_in[0];
    const void* s_feat  = d_in[1];
    const void* directs = d_in[2];
    /* d_in[3] image_shape: unused int */
    const void* disps   = d_in[4];
    const void* wq      = d_in[5];
    const void* bq      = d_in[6];
    const void* wkc     = d_in[7];
    const void* bkc     = d_in[8];
    const void* metric  = d_in[9];
    const void* alpha   = d_in[10];
    const void* beta    = d_in[11];
    const void* w_cf    = d_in[12];
    const void* b_cf    = d_in[13];
    const void* w_da    = d_in[14];
    const void* b_da    = d_in[15];
    const void* w_ex    = d_in[16];
    const void* b_ex    = d_in[17];
    const void* w_fg    = d_in[18];
    const void* b_fg    = d_in[19];
    const void* w_rd    = d_in[20];
    const void* b_rd    = d_in[21];
    const void* w_se1   = d_in[22];
    const void* w_se2   = d_in[23];
    (void)in_sizes; (void)n_in; (void)out_size; (void)d_ws; (void)ws_size;

    float* base = nullptr;
    (void)hipGetSymbolAddress((void**)&base, HIP_SYMBOL(g_scratch));
    float* qb    = base;             // slot 0
    float* kb    = base + PLN;       // slot 1
    float* Cv    = base + 2 * PLN;   // slot 2
    float* da    = base + 3 * PLN;   // slot 3
    float* Pf    = base + 4 * PLN;   // slot 4
    float* fused = base;             // slots 0-3 (q/k/Cv/da dead)
    float* xf    = base + 4 * PLN;   // slots 4-7 (Pf dead after k_fuse)

    k_detect<<<1, 256, 0, stream>>>(t_feat, wq);
    k_qk<<<dim3(H_, B_, 2), 320, 0, stream>>>(t_feat, s_feat, wq, bq, wkc, bkc, qb, kb);
    k_cost<<<dim3(H_, B_), 320, 0, stream>>>(qb, kb, metric, disps, directs,
                                             alpha, beta, w_da, b_da, Cv, da);
    k_cf_softmax<<<dim3(H_, B_), 320, 0, stream>>>(Cv, da, w_cf, b_cf, Pf, d_out);
    k_fuse<<<dim3(H_, B_), 320, 0, stream>>>(Pf, t_feat, w_ex, b_ex, w_fg, b_fg, fused);
    k_conv3<<<dim3(10, 12, 16), 128, 0, stream>>>(fused, w_rd, b_rd, xf);
    k_se<<<1, 512, 0, stream>>>(w_se1, w_se2);
    k_elu<<<(XN + 255) / 256, 256, 0, stream>>>(xf, d_out);
}

// Round 5
// 959.775 us; speedup vs baseline: 1.7726x; 1.7726x over previous
//
#include <hip/hip_runtime.h>
#include <hip/hip_bf16.h>
#include <math.h>

// HMF block, round 5: MFMA implicit-GEMM for the 3x3 conv (the 963 µs / 57%
// dispatch, previously f32 VALU-bound at MfmaUtil=0).
//  - k_fuse now writes fused as bf16 NHWC (ci contiguous) for conv staging.
//  - k_wprep transposes w_rd -> bf16 [pos][co][ci] once per launch.
//  - k_conv3: 128px x 128co block tile, mfma_f32_16x16x32_bf16, LDS-staged
//    input halo + weights, f32 accumulate, SE partial sums fused in epilogue.
// Everything else is the verified round-4 pipeline (dtype-adaptive I/O).

typedef __hip_bfloat16 bf16;
typedef unsigned short u16;
typedef __attribute__((ext_vector_type(8))) __bf16 bf16x8;
typedef __attribute__((ext_vector_type(4))) float f4;

#define DEVI static __device__ __forceinline__
DEVI float bf2f(bf16 x) { return __bfloat162float(x); }
DEVI bf16  f2bf(float x) { return __float2bfloat16(x); }
DEVI u16 bfbits(float x) { bf16 h = f2bf(x); return *(u16*)&h; }
DEVI float sigmoidf_(float x) { return 1.0f / (1.0f + expf(-x)); }

constexpr int B_ = 4, C_ = 128, H_ = 96, W_ = 320, CM = 32, D_ = 32;
constexpr int HW = H_ * W_;              // 30720
constexpr int QPLANE = CM * HW;          // 983040
constexpr int XN = B_ * C_ * HW;         // 15728640
constexpr int PLN = B_ * D_ * HW;        // 3932160

// scratch slots (floats): q=0 | k=1 | Cv=2 | da=3 | Pf=4 ; xf overlays 4-7.
__device__ __align__(16) float g_scratch[8 * PLN];
__device__ __align__(16) u16   g_fused[XN];          // bf16 NHWC
__device__ __align__(16) u16   g_wt[9 * 128 * 128];  // bf16 [pos][co][ci]
__device__ float g_ysum[512];
__device__ float g_se[512];
__device__ int   g_flag[1];

DEVI float ldin(const void* p, int i, int isb) {
    float v;
    if (isb) v = bf2f(((const bf16*)p)[i]);
    else     v = ((const float*)p)[i];
    return v;
}
DEVI void stout(void* p, int i, float v, int isb) {
    if (isb) ((bf16*)p)[i] = f2bf(v);
    else     ((float*)p)[i] = v;
}

// ---------------------------------------------------------------------------
// K0: dtype detect (t_feat + wq) + ysum zero.
__global__ __launch_bounds__(256) void k_detect(
    const void* __restrict__ t, const void* __restrict__ wqp)
{
    __shared__ int bad;
    int tid = threadIdx.x;
    if (tid == 0) bad = 0;
    __syncthreads();
    int mybad = 0;
    for (int i = tid; i < 4096; i += 256) {
        float v = bf2f(((const bf16*)t)[i]);
        if (!(v == v) || fabsf(v) > 64.0f) mybad = 1;
        float u = bf2f(((const bf16*)wqp)[i]);
        if (!(u == u) || fabsf(u) > 64.0f) mybad = 1;
    }
    if (mybad) atomicOr(&bad, 1);
    g_ysum[tid] = 0.f;
    g_ysum[tid + 256] = 0.f;
    __syncthreads();
    if (tid == 0) g_flag[0] = bad ? 0 : 1;
}

// K0b: weight transform w_rd[co][ci][pos] -> g_wt[pos][co][ci] (bf16)
__global__ __launch_bounds__(256) void k_wprep(
    const void* __restrict__ w_rd, u16* __restrict__ gw)
{
    int isb = g_flag[0];
    int i = blockIdx.x * 256 + threadIdx.x;
    if (i >= 9 * 128 * 128) return;
    int pos = i >> 14, rem = i & 16383, co = rem >> 7, ci = rem & 127;
    gw[i] = bfbits(ldin(w_rd, (co * 128 + ci) * 9 + pos, isb));
}

// ---------------------------------------------------------------------------
// K1: q = l2norm(conv1x1(t,wq,bq)), k = l2norm(conv1x1(s,wkc,bkc))
__global__ __launch_bounds__(320) void k_qk(
    const void* __restrict__ t_feat, const void* __restrict__ s_feat,
    const void* __restrict__ wq, const void* __restrict__ bq,
    const void* __restrict__ wkc, const void* __restrict__ bkc,
    float* __restrict__ qout, float* __restrict__ kout)
{
    __shared__ float WST[C_ * CM];   // [c][o]
    __shared__ float BS[CM];
    int isb = g_flag[0];
    int h = blockIdx.x, b = blockIdx.y, which = blockIdx.z;
    const void* in = which ? s_feat : t_feat;
    const void* wm = which ? wkc : wq;
    const void* bb = which ? bkc : bq;
    float* out = which ? kout : qout;
    int tid = threadIdx.x;
    for (int i = tid; i < C_ * CM; i += 320) {
        int o = i >> 7, c = i & 127;
        WST[c * CM + o] = ldin(wm, i, isb);
    }
    if (tid < CM) BS[tid] = ldin(bb, tid, isb);
    __syncthreads();
    int w = tid;
    float acc[CM];
    #pragma unroll
    for (int o = 0; o < CM; o++) acc[o] = BS[o];
    int base = (b * C_) * HW + h * W_ + w;
    for (int c = 0; c < C_; c++) {
        float v = ldin(in, base + c * HW, isb);
        #pragma unroll
        for (int o = 0; o < CM; o++) acc[o] += v * WST[c * CM + o];
    }
    float n = 0.f;
    #pragma unroll
    for (int o = 0; o < CM; o++) n += acc[o] * acc[o];
    float s = 1.0f / fmaxf(sqrtf(n), 1e-12f);
    float* op = out + (b * CM) * HW + h * W_ + w;
    #pragma unroll
    for (int o = 0; o < CM; o++) op[o * HW] = acc[o] * s;
}

// ---------------------------------------------------------------------------
// K2: warp + sim + tanh -> Cv; da = sigmoid(w_da @ [q; mean_d(warped)])
__global__ __launch_bounds__(320) void k_cost(
    const float* __restrict__ qbuf, const float* __restrict__ kbuf,
    const void* __restrict__ metric, const void* __restrict__ disps,
    const void* __restrict__ directs, const void* __restrict__ alpha_p,
    const void* __restrict__ beta_p, const void* __restrict__ w_da,
    const void* __restrict__ b_da,
    float* __restrict__ Cv, float* __restrict__ da)
{
    __shared__ float KS[CM][W_];
    __shared__ float MS[CM][CM];
    __shared__ float WDA[D_ * 64];
    __shared__ float BDA[D_];
    __shared__ float SH[D_];
    int isb = g_flag[0];
    int h = blockIdx.x, b = blockIdx.y, tid = threadIdx.x, w = tid;
    for (int i = tid; i < CM * CM; i += 320) {
        int c = i >> 5, d = i & 31;
        MS[c][d] = 0.5f * (ldin(metric, c * CM + d, isb) + ldin(metric, d * CM + c, isb));
    }
    for (int i = tid; i < D_ * 64; i += 320) WDA[i] = ldin(w_da, i, isb);
    if (tid < D_) {
        BDA[tid] = ldin(b_da, tid, isb);
        SH[tid] = ldin(disps, tid, isb) * ldin(directs, b, isb) * (float)(W_ - 1);
    }
    const float* kp = kbuf + b * QPLANE + h * W_;
    for (int c = 0; c < CM; c++) KS[c][w] = kp[c * HW + w];
    __syncthreads();

    float q[CM], qp[CM], km[CM];
    const float* qpp = qbuf + b * QPLANE + h * W_ + w;
    #pragma unroll
    for (int c = 0; c < CM; c++) q[c] = qpp[c * HW];
    #pragma unroll
    for (int d = 0; d < CM; d++) qp[d] = 0.f;
    for (int c = 0; c < CM; c++) {
        float v = q[c];
        #pragma unroll
        for (int d = 0; d < CM; d++) qp[d] += v * MS[c][d];
    }
    #pragma unroll
    for (int c = 0; c < CM; c++) km[c] = 0.f;
    float alpha = ldin(alpha_p, 0, isb), beta = ldin(beta_p, 0, isb);
    float* cvp = Cv + (b * D_) * HW + h * W_ + w;
    for (int d = 0; d < D_; d++) {
        float px = fminf(fmaxf((float)w + SH[d], 0.f), (float)(W_ - 1));
        int x0 = (int)floorf(px);
        int x1 = min(x0 + 1, W_ - 1);
        float f = px - (float)x0;
        float sim = 0.f;
        #pragma unroll
        for (int c = 0; c < CM; c++) {
            float g0 = KS[c][x0], g1 = KS[c][x1];
            float val = g0 * (1.0f - f) + g1 * f;
            sim += qp[c] * val;
            km[c] += val;
        }
        cvp[d * HW] = tanhf(alpha * sim + beta);
    }
    #pragma unroll
    for (int c = 0; c < CM; c++) km[c] *= (1.0f / (float)D_);
    float* dap = da + (b * D_) * HW + h * W_ + w;
    for (int d = 0; d < D_; d++) {
        float s = BDA[d];
        #pragma unroll
        for (int c = 0; c < CM; c++) s += WDA[d * 64 + c] * q[c];
        #pragma unroll
        for (int c = 0; c < CM; c++) s += WDA[d * 64 + 32 + c] * km[c];
        dap[d * HW] = sigmoidf_(s);
    }
}

// ---------------------------------------------------------------------------
// K3: Cf = 3x3 conv(Cv) * da -> softmax over d -> Pf (f32) + P out
__global__ __launch_bounds__(320) void k_cf_softmax(
    const float* __restrict__ Cv, const float* __restrict__ da,
    const void* __restrict__ w_cf, const void* __restrict__ b_cf,
    float* __restrict__ Pf, void* __restrict__ dout)
{
    __shared__ float R[3][322];
    int isb = g_flag[0];
    int h = blockIdx.x, b = blockIdx.y, tid = threadIdx.x, w = tid;
    float wcf[9];
    #pragma unroll
    for (int i = 0; i < 9; i++) wcf[i] = ldin(w_cf, i, isb);
    float bcf = ldin(b_cf, 0, isb);
    float vals[D_];
    for (int d = 0; d < D_; d++) {
        const float* base = Cv + ((b * D_ + d) * H_) * W_;
        #pragma unroll
        for (int r = 0; r < 3; r++) {
            int hh = h + r - 1;
            R[r][w + 1] = (hh >= 0 && hh < H_) ? base[hh * W_ + w] : 0.f;
        }
        if (tid == 0) {
            R[0][0] = R[1][0] = R[2][0] = 0.f;
            R[0][321] = R[1][321] = R[2][321] = 0.f;
        }
        __syncthreads();
        float s = bcf;
        #pragma unroll
        for (int r = 0; r < 3; r++)
            #pragma unroll
            for (int kw = 0; kw < 3; kw++)
                s += R[r][w + kw] * wcf[r * 3 + kw];
        vals[d] = s * da[((b * D_ + d) * H_ + h) * W_ + w];
        __syncthreads();
    }
    float m = vals[0];
    #pragma unroll
    for (int d = 1; d < D_; d++) m = fmaxf(m, vals[d]);
    float sum = 0.f;
    #pragma unroll
    for (int d = 0; d < D_; d++) { vals[d] = expf(vals[d] - m); sum += vals[d]; }
    float inv = 1.0f / sum;
    int o = (b * D_) * HW + h * W_ + w;
    #pragma unroll
    for (int d = 0; d < D_; d++) {
        float p = vals[d] * inv;
        Pf[o + d * HW] = p;
        stout(dout, XN + o + d * HW, p, isb);
    }
}

// ---------------------------------------------------------------------------
// K4: cost = w_ex@P+b_ex; g = sigmoid(w_fg@[t;cost]);
//     fused = g*t+(1-g)*cost  -> g_fused (bf16, NHWC)
__global__ __launch_bounds__(320) void k_fuse(
    const float* __restrict__ Pf, const void* __restrict__ t_feat,
    const void* __restrict__ w_ex, const void* __restrict__ b_ex,
    const void* __restrict__ w_fg, const void* __restrict__ b_fg,
    u16* __restrict__ gf)
{
    __shared__ float WEX[C_ * D_];   // [c][d]
    __shared__ float BEX[C_];
    __shared__ float WFG[2 * C_];
    int isb = g_flag[0];
    int h = blockIdx.x, b = blockIdx.y, tid = threadIdx.x, w = tid;
    for (int i = tid; i < C_ * D_; i += 320) WEX[i] = ldin(w_ex, i, isb);
    if (tid < C_) BEX[tid] = ldin(b_ex, tid, isb);
    for (int i = tid; i < 2 * C_; i += 320) WFG[i] = ldin(w_fg, i, isb);
    __syncthreads();
    float p[D_];
    const float* pp = Pf + (b * D_) * HW + h * W_ + w;
    #pragma unroll
    for (int d = 0; d < D_; d++) p[d] = pp[d * HW];
    int tbase = (b * C_) * HW + h * W_ + w;
    float gacc = ldin(b_fg, 0, isb);
    for (int c = 0; c < C_; c++) {
        float cost = BEX[c];
        #pragma unroll
        for (int d = 0; d < D_; d++) cost += WEX[c * D_ + d] * p[d];
        float tv = ldin(t_feat, tbase + c * HW, isb);
        gacc += WFG[c] * tv + WFG[C_ + c] * cost;
    }
    float g = sigmoidf_(gacc);
    unsigned int* gfo = (unsigned int*)gf + ((b * H_ + h) * W_ + w) * 64;
    for (int c = 0; c < C_; c += 2) {
        float c0 = BEX[c], c1 = BEX[c + 1];
        #pragma unroll
        for (int d = 0; d < D_; d++) {
            c0 += WEX[c * D_ + d] * p[d];
            c1 += WEX[(c + 1) * D_ + d] * p[d];
        }
        float t0 = ldin(t_feat, tbase + c * HW, isb);
        float t1 = ldin(t_feat, tbase + (c + 1) * HW, isb);
        float v0 = g * t0 + (1.0f - g) * c0;
        float v1 = g * t1 + (1.0f - g) * c1;
        gfo[c >> 1] = ((unsigned int)bfbits(v1) << 16) | bfbits(v0);
    }
}

// ---------------------------------------------------------------------------
// K5: x = conv3x3(fused)+b_rd via MFMA implicit GEMM.
// grid (10, 24, 4): 32w x 4h x 128co tile; block 128 (2 waves).
// Wave tile: 64 px x 128 co = 4 m-tiles x 8 n-tiles of 16x16x32 bf16 MFMA.
// LDS: input halo 6x34x32ci (pad->40) + weights 128co x 32ci (pad->40).
__global__ __launch_bounds__(128, 2) void k_conv3(
    const u16* __restrict__ gf, const u16* __restrict__ gw,
    const void* __restrict__ b_rd, float* __restrict__ xf)
{
    __shared__ u16 IN[6 * 34 * 40];
    __shared__ u16 WS[128 * 40];
    int isb = g_flag[0];
    int tid = threadIdx.x;
    int wave = tid >> 6, lane = tid & 63;
    int l15 = lane & 15, kq = lane >> 4;
    int w0 = blockIdx.x * 32, h0 = blockIdx.y * 4, b = blockIdx.z;

    f4 acc[4][8];
    #pragma unroll
    for (int mt = 0; mt < 4; mt++)
        #pragma unroll
        for (int nt = 0; nt < 8; nt++) acc[mt][nt] = (f4){0.f, 0.f, 0.f, 0.f};

    float bias[8];
    #pragma unroll
    for (int nt = 0; nt < 8; nt++) bias[nt] = ldin(b_rd, nt * 16 + l15, isb);

    for (int cb = 0; cb < 128; cb += 32) {
        __syncthreads();
        // stage input halo chunk: 6 rows x 34 cols x 32 ci (16B per thread-item)
        for (int s = tid; s < 204 * 4; s += 128) {
            int p = s >> 2, q = s & 3;
            int hp = p / 34, wp = p - hp * 34;
            int hg = h0 - 1 + hp, wg = w0 - 1 + wp;
            uint4 v = make_uint4(0u, 0u, 0u, 0u);
            if (hg >= 0 && hg < H_ && wg >= 0 && wg < W_)
                v = *(const uint4*)(gf + ((((b * H_ + hg) * W_ + wg) << 7) + cb + q * 8));
            *(uint4*)(&IN[(hp * 34 + wp) * 40 + q * 8]) = v;
        }
        for (int pos = 0; pos < 9; pos++) {
            __syncthreads();
            for (int s = tid; s < 128 * 4; s += 128) {
                int co = s >> 2, q = s & 3;
                *(uint4*)(&WS[co * 40 + q * 8]) =
                    *(const uint4*)(gw + (((pos * 128 + co) << 7) + cb + q * 8));
            }
            __syncthreads();
            int kh = pos / 3, kw = pos - kh * 3;
            bf16x8 bfr[8];
            #pragma unroll
            for (int nt = 0; nt < 8; nt++)
                bfr[nt] = *(bf16x8*)(&WS[(nt * 16 + l15) * 40 + kq * 8]);
            #pragma unroll
            for (int mt = 0; mt < 4; mt++) {
                int px = wave * 64 + mt * 16 + l15;
                int row = (px >> 5) + kh, col = (px & 31) + kw;
                bf16x8 afr = *(bf16x8*)(&IN[(row * 34 + col) * 40 + kq * 8]);
                #pragma unroll
                for (int nt = 0; nt < 8; nt++)
                    acc[mt][nt] = __builtin_amdgcn_mfma_f32_16x16x32_bf16(
                        afr, bfr[nt], acc[mt][nt], 0, 0, 0);
            }
        }
    }
    // epilogue: bias, store x (f32 NCHW), SE partial sums
    #pragma unroll
    for (int nt = 0; nt < 8; nt++) {
        int co = nt * 16 + l15;
        float ps = 0.f;
        #pragma unroll
        for (int mt = 0; mt < 4; mt++) {
            #pragma unroll
            for (int r = 0; r < 4; r++) {
                int px = wave * 64 + mt * 16 + kq * 4 + r;
                float v = acc[mt][nt][r] + bias[nt];
                ps += v;
                xf[((b * C_ + co) * H_ + h0 + (px >> 5)) * W_ + w0 + (px & 31)] = v;
            }
        }
        ps += __shfl_xor(ps, 16);
        ps += __shfl_xor(ps, 32);
        if (lane < 16) atomicAdd(&g_ysum[b * C_ + co], ps);
    }
}

// ---------------------------------------------------------------------------
// K6: SE scale per (b,c)
__global__ __launch_bounds__(512) void k_se(
    const void* __restrict__ w_se1, const void* __restrict__ w_se2)
{
    __shared__ float YM[B_ * C_];
    __shared__ float Y1[B_ * 8];
    int isb = g_flag[0];
    int tid = threadIdx.x;
    YM[tid] = g_ysum[tid] * (1.0f / (float)HW);
    __syncthreads();
    if (tid < 32) {
        int b = tid >> 3, j = tid & 7;
        float s = 0.f;
        for (int c = 0; c < C_; c++) s += YM[b * C_ + c] * ldin(w_se1, j * C_ + c, isb);
        Y1[tid] = fmaxf(s, 0.f);
    }
    __syncthreads();
    int b = tid >> 7, c = tid & 127;
    float s = 0.f;
    #pragma unroll
    for (int j = 0; j < 8; j++) s += Y1[b * 8 + j] * ldin(w_se2, c * 8 + j, isb);
    g_se[tid] = sigmoidf_(s);
}

// K7: out_x = elu(xf32 * se), in detected output dtype
__global__ __launch_bounds__(256) void k_elu(
    const float* __restrict__ xf, void* __restrict__ dout)
{
    int isb = g_flag[0];
    int idx = blockIdx.x * 256 + threadIdx.x;
    if (idx >= XN) return;
    int plane = idx / HW;
    float v = xf[idx] * g_se[plane];
    stout(dout, idx, v > 0.f ? v : expm1f(v), isb);
}

// ---------------------------------------------------------------------------
extern "C" void kernel_launch(void* const* d_in, const int* in_sizes, int n_in,
                              void* d_out, int out_size, void* d_ws, size_t ws_size,
                              hipStream_t stream)
{
    const void* t_feat  = d_in[0];
    const void* s_feat  = d_in[1];
    const void* directs = d_in[2];
    /* d_in[3] image_shape: unused */
    const void* disps   = d_in[4];
    const void* wq      = d_in[5];
    const void* bq      = d_in[6];
    const void* wkc     = d_in[7];
    const void* bkc     = d_in[8];
    const void* metric  = d_in[9];
    const void* alpha   = d_in[10];
    const void* beta    = d_in[11];
    const void* w_cf    = d_in[12];
    const void* b_cf    = d_in[13];
    const void* w_da    = d_in[14];
    const void* b_da    = d_in[15];
    const void* w_ex    = d_in[16];
    const void* b_ex    = d_in[17];
    const void* w_fg    = d_in[18];
    const void* b_fg    = d_in[19];
    const void* w_rd    = d_in[20];
    const void* b_rd    = d_in[21];
    const void* w_se1   = d_in[22];
    const void* w_se2   = d_in[23];
    (void)in_sizes; (void)n_in; (void)out_size; (void)d_ws; (void)ws_size;

    float* base = nullptr;
    (void)hipGetSymbolAddress((void**)&base, HIP_SYMBOL(g_scratch));
    u16* gf = nullptr;
    (void)hipGetSymbolAddress((void**)&gf, HIP_SYMBOL(g_fused));
    u16* gw = nullptr;
    (void)hipGetSymbolAddress((void**)&gw, HIP_SYMBOL(g_wt));
    float* qb = base;
    float* kb = base + PLN;
    float* Cv = base + 2 * PLN;
    float* da = base + 3 * PLN;
    float* Pf = base + 4 * PLN;
    float* xf = base + 4 * PLN;      // overlays Pf (dead after k_fuse)

    k_detect<<<1, 256, 0, stream>>>(t_feat, wq);
    k_wprep<<<576, 256, 0, stream>>>(w_rd, gw);
    k_qk<<<dim3(H_, B_, 2), 320, 0, stream>>>(t_feat, s_feat, wq, bq, wkc, bkc, qb, kb);
    k_cost<<<dim3(H_, B_), 320, 0, stream>>>(qb, kb, metric, disps, directs,
                                             alpha, beta, w_da, b_da, Cv, da);
    k_cf_softmax<<<dim3(H_, B_), 320, 0, stream>>>(Cv, da, w_cf, b_cf, Pf, d_out);
    k_fuse<<<dim3(H_, B_), 320, 0, stream>>>(Pf, t_feat, w_ex, b_ex, w_fg, b_fg, gf);
    k_conv3<<<dim3(10, 24, 4), 128, 0, stream>>>(gf, gw, b_rd, xf);
    k_se<<<1, 512, 0, stream>>>(w_se1, w_se2);
    k_elu<<<(XN + 255) / 256, 256, 0, stream>>>(xf, d_out);
}